// Round 10
// baseline (243.810 us; speedup 1.0000x reference)
//
#include <hip/hip_runtime.h>
#include <math.h>

// edge = a*box5(x) + b*box3(x) + c*x   (fused K5+K3 depthwise conv, zero pad)
// out  = abs(maxpool5(edge))           (maxpool pads with -inf; v-max then h-max)
//
// No-LDS register pipeline (R3 structure) + P=4 ROTATING PREFETCH: step t
// consumes pf[t%4] (compiler emits s_waitcnt vmcnt(3) -> 3 loads always in
// flight) and immediately issues the row t+4 load into the freed slot.
// sched_group_barrier pins the interleave (1 VMEM_READ : ~80 VALU per step)
// so the compiler cannot re-sink the loads to their uses (R6 failure mode:
// VGPR 48 proved the burst got sunk; plateau 2.5 TB/s across R3-R8 is
// latency exposure, not BW -- harness fillBuffer hits 6.5 TB/s on this chip).
// E/V forward accumulation verbatim from R5..R8 (absmax 0.03125).
// __launch_bounds__(256,4): cap 128 >= need (~95). R4 lesson: never cap below.

#define TY    16
#define STEPS (TY + 8)     // 24
#define PF    4

typedef float vfloat4 __attribute__((ext_vector_type(4)));

__global__ __launch_bounds__(256, 4)
void edgepool_kernel(const float* __restrict__ xin, float* __restrict__ yout) {
    const int lane  = threadIdx.x & 63;
    const int wave  = threadIdx.x >> 6;
    const int blk   = blockIdx.x;                 // 0..2047
    const int plane = blk >> 2;                   // 0..511
    const int strip = ((blk & 3) << 2) | wave;    // 0..15 (adjacent strips/block)
    const int y0    = strip * TY;

    const float4* __restrict__ in4  = (const float4*)xin + (size_t)plane * 16384;
    vfloat4*      __restrict__ out4 = (vfloat4*)    yout + (size_t)plane * 16384;

    const float Wa = -0.01f, Wb = -0.19f, Wc = 2.2f;
    const float NINF = -INFINITY;

    // ---- prologue: fill the 4-slot rotating prefetch ring ----
    float4 pf[PF];
#pragma unroll
    for (int t = 0; t < PF; ++t) {
        const int r  = y0 - 4 + t;
        const int rc = (r < 0) ? 0 : (r > 255 ? 255 : r);
        pf[t] = in4[rc * 64 + lane];
    }

    float E[5][4];   // cyclic edge-row accumulators (conv partial sums)
    float V[5][4];   // cyclic vertical-5-max accumulators
#pragma unroll
    for (int k = 0; k < 5; ++k)
#pragma unroll
        for (int j = 0; j < 4; ++j) { E[k][j] = 0.f; V[k][j] = NINF; }

#pragma unroll
    for (int t = 0; t < STEPS; ++t) {
        const int  r   = y0 - 4 + t;
        const bool rin = (unsigned)r < 256u;

        // consume slot (auto s_waitcnt vmcnt(PF-1)), then refill with row t+PF
        const float4 cur = pf[t % PF];
        if (t + PF < STEPS) {
            const int rn  = y0 - 4 + t + PF;
            const int rcn = (rn < 0) ? 0 : (rn > 255 ? 255 : rn);
            pf[t % PF] = in4[rcn * 64 + lane];
            __builtin_amdgcn_sched_group_barrier(0x020, 1, 0);   // exactly 1 VMEM read here
        }

        const float v0 = rin ? cur.x : 0.f;
        const float v1 = rin ? cur.y : 0.f;
        const float v2 = rin ? cur.z : 0.f;
        const float v3 = rin ? cur.w : 0.f;

        // horizontal halo from neighbor lanes (zero-pad image edges)
        float lm2 = __shfl(v2, lane - 1, 64);
        float lm1 = __shfl(v3, lane - 1, 64);
        float rp0 = __shfl(v0, lane + 1, 64);
        float rp1 = __shfl(v1, lane + 1, 64);
        lm2 = (lane == 0)  ? 0.f : lm2;
        lm1 = (lane == 0)  ? 0.f : lm1;
        rp0 = (lane == 63) ? 0.f : rp0;
        rp1 = (lane == 63) ? 0.f : rp1;

        // horizontal box sums
        const float s01 = v0 + v1, s23 = v2 + v3;
        const float h3[4] = { lm1 + s01, s01 + v2, v1 + s23, s23 + rp0 };
        const float h5[4] = { lm2 + lm1 + s01 + v2, lm1 + s01 + s23,
                              s01 + s23 + rp0,      v1 + s23 + rp0 + rp1 };
        const float vv[4] = { v0, v1, v2, v3 };

        // cyclic slots (compile-time after full unroll)
        const int e2 = (t + 2) % 5, e1 = (t + 1) % 5, e0 = t % 5,
                  em1 = (t + 4) % 5, em2 = (t + 3) % 5;

        // scatter this row into the 5 live edge accumulators
#pragma unroll
        for (int j = 0; j < 4; ++j) {
            E[e2][j]  = Wa * h5[j];                                      // init row r+2
            E[e1][j]  = fmaf(Wb, h3[j], fmaf(Wa, h5[j], E[e1][j]));
            E[e0][j]  = fmaf(Wc, vv[j], fmaf(Wb, h3[j], fmaf(Wa, h5[j], E[e0][j])));
            E[em1][j] = fmaf(Wb, h3[j], fmaf(Wa, h5[j], E[em1][j]));
            E[em2][j] = fmaf(Wa, h5[j], E[em2][j]);                      // completes row r-2
        }

        // edge row er = r-2 complete; -inf outside image for the maxpool
        const int  er  = r - 2;
        const bool ein = (unsigned)er < 256u;
        float e[4];
#pragma unroll
        for (int j = 0; j < 4; ++j) e[j] = ein ? E[em2][j] : NINF;

        // scatter edge row into the 5 live vertical-max accumulators
#pragma unroll
        for (int j = 0; j < 4; ++j) {
            V[e2][j]  = e[j];                          // init for output row er+2
            V[e1][j]  = fmaxf(V[e1][j], e[j]);
            V[e0][j]  = fmaxf(V[e0][j], e[j]);
            V[em1][j] = fmaxf(V[em1][j], e[j]);
            V[em2][j] = fmaxf(V[em2][j], e[j]);        // completes output row r-4
        }

        // output row o = r-4: horizontal 5-max of completed V row + abs + store
        if (t >= 8) {   // compile-time predicate after unroll
            const float m0 = V[em2][0], m1 = V[em2][1], m2 = V[em2][2], m3 = V[em2][3];
            float ml2 = __shfl(m2, lane - 1, 64);
            float ml1 = __shfl(m3, lane - 1, 64);
            float mr0 = __shfl(m0, lane + 1, 64);
            float mr1 = __shfl(m1, lane + 1, 64);
            ml2 = (lane == 0)  ? NINF : ml2;
            ml1 = (lane == 0)  ? NINF : ml1;
            mr0 = (lane == 63) ? NINF : mr0;
            mr1 = (lane == 63) ? NINF : mr1;
            vfloat4 ov;
            ov.x = fabsf(fmaxf(fmaxf(ml2, ml1), fmaxf(fmaxf(m0, m1), m2)));
            ov.y = fabsf(fmaxf(fmaxf(ml1, m0), fmaxf(fmaxf(m1, m2), m3)));
            ov.z = fabsf(fmaxf(fmaxf(m0, m1), fmaxf(fmaxf(m2, m3), mr0)));
            ov.w = fabsf(fmaxf(fmaxf(m1, m2), fmaxf(fmaxf(m3, mr0), mr1)));
            __builtin_nontemporal_store(ov, &out4[(r - 4) * 64 + lane]);
        }

        // pin the per-step VALU cluster behind the load (keeps 1:~80 interleave)
        __builtin_amdgcn_sched_group_barrier(0x002, 80, 0);
    }
}

extern "C" void kernel_launch(void* const* d_in, const int* in_sizes, int n_in,
                              void* d_out, int out_size, void* d_ws, size_t ws_size,
                              hipStream_t stream) {
    const float* x   = (const float*)d_in[0];
    float*       out = (float*)d_out;
    // 512 planes x 16 strips = 8192 wave-tasks; 4 waves/block -> 2048 blocks.
    hipLaunchKernelGGL(edgepool_kernel, dim3(2048), dim3(256), 0, stream, x, out);
}